// Round 1
// baseline (624.034 us; speedup 1.0000x reference)
//
#include <hip/hip_runtime.h>

// VQ-VAE codebook quantization — R13: de-LDS the screen + overlap j0 stores
// with j1 screen.
// x: (4096, 1024) f32; codebook: (128, 256, 8) f32.
// out = [cw_embed (4096*1024 f32) | one_hot (4096*128*256 f32)].
//
// Theory for this round: R8's ~142us kernel = LDS-broadcast-bound screen
// (~50us: 36B x 64-lane replicated return per k per wave, ~2.4GB total
// through the LDS return network) serialized before the HBM write phase
// (~91us floor). Fix: codeword reads are block-uniform -> read from global
// as uniform f32x8 so the compiler emits s_load_dwordx8 (64B/wave, no
// per-lane replication). That makes a per-j split free (R8's fused-j loop
// existed only to amortize LDS reads), so j0's one-hot bursts are
// interleaved into j1's screen loop: j0's ~43us HBM drain overlaps j1's
// ~12us VALU screen instead of serializing.
//
// Unchanged from R8 (proven exact, absmax 0.0): fp32 top-2 screen
// arithmetic (identical fmaf order), LDS-staged s_cbf/s_c2f (repair +
// embed source + c2), wave-cooperative fp64 repair of gap<=TAU2 pairs,
// cached full-line one-hot bursts, 32B embed stores, grid (128,8) x 256,
// 4 blocks/CU.

constexpr int B_  = 4096;
constexpr int C_  = 128;
constexpr int K_  = 256;
constexpr int D_  = 8;
constexpr int TPB = 256;

constexpr int   BPT   = 2;           // pairs per thread
constexpr int   BTILE = TPB * BPT;   // 512 b per block
constexpr float TAU2  = 1.0e-3f;     // ambiguity gap threshold

typedef float vf4   __attribute__((ext_vector_type(4)));
typedef float f32x8 __attribute__((ext_vector_type(8)));

// Wave-cooperative exact fp64 re-argmin of ambiguous rows (identical to R8).
__device__ __forceinline__ void repair_amb(
    const float xfj[D_], int& k1j, const float s1j, const float s2j,
    const float* s_cbf, const int lane)
{
    const bool amb = (s2j - s1j) <= TAU2;
    unsigned long long mask = __ballot(amb);
    while (mask) {
        const int src = (int)__ffsll((long long)mask) - 1;
        mask &= mask - 1;
        double xd[D_];
        #pragma unroll
        for (int d = 0; d < D_; ++d) xd[d] = (double)__shfl(xfj[d], src);
        double best = 1.0e300;
        int    bk   = 0;
        #pragma unroll
        for (int t = 0; t < 4; ++t) {
            const int k = lane * 4 + t;      // ascending k within lane
            const float* cv = s_cbf + k * D_;
            double cd[D_];
            #pragma unroll
            for (int d = 0; d < D_; ++d) cd[d] = (double)cv[d];
            double c2k = 0.0;
            #pragma unroll
            for (int d = 0; d < D_; ++d) c2k = fma(cd[d], cd[d], c2k);
            double dot = xd[0] * cd[0];
            #pragma unroll
            for (int d = 1; d < D_; ++d) dot = fma(xd[d], cd[d], dot);
            const double score = fma(-2.0, dot, c2k);
            if (score < best) { best = score; bk = k; }  // first-min
        }
        #pragma unroll
        for (int off = 32; off >= 1; off >>= 1) {
            const double ob  = __shfl_down(best, off);
            const int    obk = __shfl_down(bk,   off);
            if (ob < best) { best = ob; bk = obk; }  // tie -> lower k
        }
        const int win = __shfl(bk, 0);
        if (lane == src) k1j = win;
    }
}

__global__ __launch_bounds__(TPB) void vq_fused(
    const float* __restrict__ x,
    const float* __restrict__ cb,
    float* __restrict__ out_embed,
    float* __restrict__ out_onehot)
{
    __shared__ float s_cbf[K_ * D_];  // 8 KB fp32 codebook slice (repair+embed)
    __shared__ float s_c2f[K_];       // 1 KB fp32 ||c_k||^2

    const int c    = blockIdx.x;   // 0..127
    const int bt   = blockIdx.y;   // 0..7
    const int tid  = threadIdx.x;
    const int lane = tid & 63;
    const int wave = tid >> 6;

    // ---- stage codebook slice + c2 (values identical to global cb) ----
    {
        const float4* gcb = (const float4*)(cb + (size_t)c * (K_ * D_));
        ((float4*)s_cbf)[tid]       = gcb[tid];
        ((float4*)s_cbf)[tid + TPB] = gcb[tid + TPB];
    }
    __syncthreads();
    {
        const float* v = s_cbf + tid * D_;
        float s = 0.f;
        #pragma unroll
        for (int d = 0; d < D_; ++d) s = fmaf(v[d], v[d], s);
        s_c2f[tid] = s;
    }
    __syncthreads();
    // LDS read-only below; k1 lives in registers — no more barriers.

    const int bbase = bt * BTILE;

    // Uniform (block-constant address) codeword stream: the screen reads the
    // codebook straight from global so the compiler can scalarize to
    // s_load_dwordx8 — one 64B return per wave instead of a 64-lane LDS
    // broadcast replication. Bit-identical values to s_cbf.
    const f32x8* __restrict__ cbs8 = (const f32x8*)(cb + (size_t)c * (K_ * D_));

    // ---- x fragments (both pairs up front, as R8) ----
    float xf0[D_], xf1[D_];
    {
        const float4* xp = (const float4*)(x + (size_t)(bbase + tid) * (C_ * D_) + c * D_);
        const float4 a = xp[0];
        const float4 h = xp[1];
        xf0[0] = a.x; xf0[1] = a.y; xf0[2] = a.z; xf0[3] = a.w;
        xf0[4] = h.x; xf0[5] = h.y; xf0[6] = h.z; xf0[7] = h.w;
    }
    {
        const float4* xp = (const float4*)(x + (size_t)(bbase + TPB + tid) * (C_ * D_) + c * D_);
        const float4 a = xp[0];
        const float4 h = xp[1];
        xf1[0] = a.x; xf1[1] = a.y; xf1[2] = a.z; xf1[3] = a.w;
        xf1[4] = h.x; xf1[5] = h.y; xf1[6] = h.z; xf1[7] = h.w;
    }

    // ---- fp32 top-2 screen, j = 0 (scalar codebook loads) ----
    float s1_0 = 3.4e38f, s2_0 = 3.4e38f;
    int   k1_0 = 0;
    #pragma unroll 2
    for (int k = 0; k < K_; ++k) {
        const f32x8 cw  = cbs8[k];
        const float c2k = s_c2f[k];
        float dot = xf0[0] * cw[0];
        dot = fmaf(xf0[1], cw[1], dot);
        dot = fmaf(xf0[2], cw[2], dot);
        dot = fmaf(xf0[3], cw[3], dot);
        dot = fmaf(xf0[4], cw[4], dot);
        dot = fmaf(xf0[5], cw[5], dot);
        dot = fmaf(xf0[6], cw[6], dot);
        dot = fmaf(xf0[7], cw[7], dot);
        const float score = fmaf(-2.f, dot, c2k);
        // top-2 (s2 uses OLD s1; strict < keeps first-index winner)
        s2_0 = fminf(s2_0, fmaxf(score, s1_0));
        const bool lt = score < s1_0;
        k1_0 = lt ? k : k1_0;
        s1_0 = lt ? score : s1_0;
    }

    // ---- repair j0, then its embed write (32B from LDS slice) ----
    repair_amb(xf0, k1_0, s1_0, s2_0, s_cbf, lane);
    {
        const size_t pair = (size_t)(bbase + tid) * C_ + c;
        float4* dst = (float4*)(out_embed + pair * D_);
        dst[0] = ((const float4*)s_cbf)[k1_0 * 2];
        dst[1] = ((const float4*)s_cbf)[k1_0 * 2 + 1];
    }

    // ---- screen j = 1 fused with j0's one-hot bursts ----
    // One full-wave 1KB contiguous store every 4th k: j0's ~43us GPU-wide
    // HBM drain overlaps j1's VALU screen instead of serializing after it.
    const int bw0 = bbase + wave * 64;
    const int e0  = lane * 4;
    float s1_1 = 3.4e38f, s2_1 = 3.4e38f;
    int   k1_1 = 0;
    #pragma unroll 4
    for (int k = 0; k < K_; ++k) {
        const f32x8 cw  = cbs8[k];
        const float c2k = s_c2f[k];
        float dot = xf1[0] * cw[0];
        dot = fmaf(xf1[1], cw[1], dot);
        dot = fmaf(xf1[2], cw[2], dot);
        dot = fmaf(xf1[3], cw[3], dot);
        dot = fmaf(xf1[4], cw[4], dot);
        dot = fmaf(xf1[5], cw[5], dot);
        dot = fmaf(xf1[6], cw[6], dot);
        dot = fmaf(xf1[7], cw[7], dot);
        const float score = fmaf(-2.f, dot, c2k);
        s2_1 = fminf(s2_1, fmaxf(score, s1_1));
        const bool lt = score < s1_1;
        k1_1 = lt ? k : k1_1;
        s1_1 = lt ? score : s1_1;

        if ((k & 3) == 0) {               // static under unroll 4
            const int i  = k >> 2;        // row 0..63
            const int kk = __builtin_amdgcn_readlane(k1_0, i);
            vf4 v;
            v.x = (kk == e0    ) ? 1.f : 0.f;
            v.y = (kk == e0 + 1) ? 1.f : 0.f;
            v.z = (kk == e0 + 2) ? 1.f : 0.f;
            v.w = (kk == e0 + 3) ? 1.f : 0.f;
            const size_t row = (size_t)(bw0 + i) * C_ + c;
            ((vf4*)(out_onehot + row * K_))[lane] = v;
        }
    }

    // ---- repair j1 + its writes (as R8) ----
    repair_amb(xf1, k1_1, s1_1, s2_1, s_cbf, lane);
    {
        const size_t pair = (size_t)(bbase + TPB + tid) * C_ + c;
        float4* dst = (float4*)(out_embed + pair * D_);
        dst[0] = ((const float4*)s_cbf)[k1_1 * 2];
        dst[1] = ((const float4*)s_cbf)[k1_1 * 2 + 1];
    }
    {
        const int bw1 = bbase + TPB + wave * 64;
        #pragma unroll 8
        for (int i = 0; i < 64; ++i) {
            const int kk = __builtin_amdgcn_readlane(k1_1, i);
            vf4 v;
            v.x = (kk == e0    ) ? 1.f : 0.f;
            v.y = (kk == e0 + 1) ? 1.f : 0.f;
            v.z = (kk == e0 + 2) ? 1.f : 0.f;
            v.w = (kk == e0 + 3) ? 1.f : 0.f;
            const size_t row = (size_t)(bw1 + i) * C_ + c;
            ((vf4*)(out_onehot + row * K_))[lane] = v;
        }
    }
}

extern "C" void kernel_launch(void* const* d_in, const int* in_sizes, int n_in,
                              void* d_out, int out_size, void* d_ws, size_t ws_size,
                              hipStream_t stream) {
    const float* x  = (const float*)d_in[0];
    const float* cb = (const float*)d_in[1];
    float* out        = (float*)d_out;
    float* out_embed  = out;                          // 4096*1024
    float* out_onehot = out + (size_t)B_ * C_ * D_;   // 4096*128*256

    dim3 grid(C_, B_ / BTILE);  // (128, 8) = 1024 blocks, 4 per CU
    vq_fused<<<grid, TPB, 0, stream>>>(x, cb, out_embed, out_onehot);
}

// Round 2
// 607.178 us; speedup vs baseline: 1.0278x; 1.0278x over previous
//
#include <hip/hip_runtime.h>

// VQ-VAE codebook quantization — R14: register/readlane screen + j-split
// overlap (j0 one-hot bursts interleaved into j1 screen).
// x: (4096, 1024) f32; codebook: (128, 256, 8) f32.
// out = [cw_embed (4096*1024 f32) | one_hot (4096*128*256 f32)].
//
// Post-mortem R13 (624us, +42 vs R8): SMEM screen serialized — s_load and
// ds_read share lgkmcnt and SMEM returns out-of-order, forcing
// lgkmcnt(0) per iteration at scalar-cache/L2 latency; 4x8KB slices also
// thrash K$. Both j loops paid it.
//
// R14 theory: R8's screen is LDS-return-pipe-bound (broadcast codeword
// read ~30cyc/k/wave x 16 waves sharing one LDS unit ~= 51us, HBM idle),
// serialized before the ~91us write drain. Old "per-j interleave" was
// neutral because splitting DOUBLED LDS traffic. Fix: codewords live in
// per-lane registers (lane holds k = g*64+lane, g=0..3; 36 VGPRs) and the
// loop broadcasts via v_readlane (uniform lane index -> SGPR, legal as the
// one SGPR operand of v_fmac). Pure-VALU loop, no lgkmcnt, 4 SIMDs in
// parallel. j-split is now cheap -> j0's one-hot HBM drain overlaps j1's
// VALU screen.
//
// Unchanged from R8 (proven exact, absmax 0.0 across R2-R13): fp32 top-2
// fmaf chain (bit-identical values, source is the same staged data), LDS
// s_cbf/s_c2f for repair + embed gather + reg init, wave-cooperative fp64
// repair of gap<=TAU2, cached full-line one-hot bursts, 32B embed stores,
// grid (128,8) x 256.

constexpr int B_  = 4096;
constexpr int C_  = 128;
constexpr int K_  = 256;
constexpr int D_  = 8;
constexpr int TPB = 256;

constexpr int   BPT   = 2;           // pairs per thread
constexpr int   BTILE = TPB * BPT;   // 512 b per block
constexpr float TAU2  = 1.0e-3f;     // ambiguity gap threshold

typedef float vf4 __attribute__((ext_vector_type(4)));

__device__ __forceinline__ float bcast_lane(float v, int lane) {
    return __builtin_bit_cast(float,
        __builtin_amdgcn_readlane(__builtin_bit_cast(int, v), lane));
}

// Wave-cooperative exact fp64 re-argmin of ambiguous rows (identical to R8).
__device__ __forceinline__ void repair_amb(
    const float xfj[D_], int& k1j, const float s1j, const float s2j,
    const float* s_cbf, const int lane)
{
    const bool amb = (s2j - s1j) <= TAU2;
    unsigned long long mask = __ballot(amb);
    while (mask) {
        const int src = (int)__ffsll((long long)mask) - 1;
        mask &= mask - 1;
        double xd[D_];
        #pragma unroll
        for (int d = 0; d < D_; ++d) xd[d] = (double)__shfl(xfj[d], src);
        double best = 1.0e300;
        int    bk   = 0;
        #pragma unroll
        for (int t = 0; t < 4; ++t) {
            const int k = lane * 4 + t;      // ascending k within lane
            const float* cv = s_cbf + k * D_;
            double cd[D_];
            #pragma unroll
            for (int d = 0; d < D_; ++d) cd[d] = (double)cv[d];
            double c2k = 0.0;
            #pragma unroll
            for (int d = 0; d < D_; ++d) c2k = fma(cd[d], cd[d], c2k);
            double dot = xd[0] * cd[0];
            #pragma unroll
            for (int d = 1; d < D_; ++d) dot = fma(xd[d], cd[d], dot);
            const double score = fma(-2.0, dot, c2k);
            if (score < best) { best = score; bk = k; }  // first-min
        }
        #pragma unroll
        for (int off = 32; off >= 1; off >>= 1) {
            const double ob  = __shfl_down(best, off);
            const int    obk = __shfl_down(bk,   off);
            if (ob < best) { best = ob; bk = obk; }  // tie -> lower k
        }
        const int win = __shfl(bk, 0);
        if (lane == src) k1j = win;
    }
}

__global__ __launch_bounds__(TPB, 4) void vq_fused(
    const float* __restrict__ x,
    const float* __restrict__ cb,
    float* __restrict__ out_embed,
    float* __restrict__ out_onehot)
{
    __shared__ float s_cbf[K_ * D_];  // 8 KB fp32 codebook slice
    __shared__ float s_c2f[K_];       // 1 KB fp32 ||c_k||^2

    const int c    = blockIdx.x;   // 0..127
    const int bt   = blockIdx.y;   // 0..7
    const int tid  = threadIdx.x;
    const int lane = tid & 63;
    const int wave = tid >> 6;

    // ---- stage codebook slice + c2 ----
    {
        const float4* gcb = (const float4*)(cb + (size_t)c * (K_ * D_));
        ((float4*)s_cbf)[tid]       = gcb[tid];
        ((float4*)s_cbf)[tid + TPB] = gcb[tid + TPB];
    }
    __syncthreads();
    {
        const float* v = s_cbf + tid * D_;
        float s = 0.f;
        #pragma unroll
        for (int d = 0; d < D_; ++d) s = fmaf(v[d], v[d], s);
        s_c2f[tid] = s;
    }
    __syncthreads();
    // LDS read-only below; k1 lives in registers — no more barriers.

    const int bbase = bt * BTILE;

    // ---- per-lane codeword registers: lane holds k = g*64 + lane ----
    // 4 groups x 8 floats + 4 c2 = 36 VGPRs. One-time LDS reads; the screen
    // loop itself touches no memory (readlane broadcast only).
    float cwreg[4][D_];
    float c2reg[4];
    #pragma unroll
    for (int g = 0; g < 4; ++g) {
        const int k = g * 64 + lane;
        const float4 lo = ((const float4*)s_cbf)[k * 2];
        const float4 hi = ((const float4*)s_cbf)[k * 2 + 1];
        cwreg[g][0] = lo.x; cwreg[g][1] = lo.y; cwreg[g][2] = lo.z; cwreg[g][3] = lo.w;
        cwreg[g][4] = hi.x; cwreg[g][5] = hi.y; cwreg[g][6] = hi.z; cwreg[g][7] = hi.w;
        c2reg[g] = s_c2f[k];
    }

    // ---- x fragments ----
    float xf0[D_], xf1[D_];
    {
        const float4* xp = (const float4*)(x + (size_t)(bbase + tid) * (C_ * D_) + c * D_);
        const float4 a = xp[0];
        const float4 h = xp[1];
        xf0[0] = a.x; xf0[1] = a.y; xf0[2] = a.z; xf0[3] = a.w;
        xf0[4] = h.x; xf0[5] = h.y; xf0[6] = h.z; xf0[7] = h.w;
    }
    {
        const float4* xp = (const float4*)(x + (size_t)(bbase + TPB + tid) * (C_ * D_) + c * D_);
        const float4 a = xp[0];
        const float4 h = xp[1];
        xf1[0] = a.x; xf1[1] = a.y; xf1[2] = a.z; xf1[3] = a.w;
        xf1[4] = h.x; xf1[5] = h.y; xf1[6] = h.z; xf1[7] = h.w;
    }

    // ---- fp32 top-2 screen, j = 0 (pure VALU: readlane broadcast) ----
    float s1_0 = 3.4e38f, s2_0 = 3.4e38f;
    int   k1_0 = 0;
    #pragma unroll
    for (int g = 0; g < 4; ++g) {
        #pragma unroll 4
        for (int i = 0; i < 64; ++i) {
            const int k = g * 64 + i;
            float cw[D_];
            #pragma unroll
            for (int d = 0; d < D_; ++d) cw[d] = bcast_lane(cwreg[g][d], i);
            const float c2k = bcast_lane(c2reg[g], i);
            float dot = xf0[0] * cw[0];
            dot = fmaf(xf0[1], cw[1], dot);
            dot = fmaf(xf0[2], cw[2], dot);
            dot = fmaf(xf0[3], cw[3], dot);
            dot = fmaf(xf0[4], cw[4], dot);
            dot = fmaf(xf0[5], cw[5], dot);
            dot = fmaf(xf0[6], cw[6], dot);
            dot = fmaf(xf0[7], cw[7], dot);
            const float score = fmaf(-2.f, dot, c2k);
            // top-2 (s2 uses OLD s1; strict < keeps first-index winner)
            s2_0 = fminf(s2_0, fmaxf(score, s1_0));
            const bool lt = score < s1_0;
            k1_0 = lt ? k : k1_0;
            s1_0 = lt ? score : s1_0;
        }
    }

    // ---- repair j0, then its embed write (32B from LDS slice) ----
    repair_amb(xf0, k1_0, s1_0, s2_0, s_cbf, lane);
    {
        const size_t pair = (size_t)(bbase + tid) * C_ + c;
        float4* dst = (float4*)(out_embed + pair * D_);
        dst[0] = ((const float4*)s_cbf)[k1_0 * 2];
        dst[1] = ((const float4*)s_cbf)[k1_0 * 2 + 1];
    }

    // ---- screen j = 1 fused with j0's one-hot bursts ----
    // One full-wave 1KB contiguous store every 4th k: j0's HBM drain
    // overlaps j1's pure-VALU screen.
    const int bw0 = bbase + wave * 64;
    const int e0  = lane * 4;
    float s1_1 = 3.4e38f, s2_1 = 3.4e38f;
    int   k1_1 = 0;
    #pragma unroll
    for (int g = 0; g < 4; ++g) {
        #pragma unroll 4
        for (int i = 0; i < 64; ++i) {
            const int k = g * 64 + i;
            float cw[D_];
            #pragma unroll
            for (int d = 0; d < D_; ++d) cw[d] = bcast_lane(cwreg[g][d], i);
            const float c2k = bcast_lane(c2reg[g], i);
            float dot = xf1[0] * cw[0];
            dot = fmaf(xf1[1], cw[1], dot);
            dot = fmaf(xf1[2], cw[2], dot);
            dot = fmaf(xf1[3], cw[3], dot);
            dot = fmaf(xf1[4], cw[4], dot);
            dot = fmaf(xf1[5], cw[5], dot);
            dot = fmaf(xf1[6], cw[6], dot);
            dot = fmaf(xf1[7], cw[7], dot);
            const float score = fmaf(-2.f, dot, c2k);
            s2_1 = fminf(s2_1, fmaxf(score, s1_1));
            const bool lt = score < s1_1;
            k1_1 = lt ? k : k1_1;
            s1_1 = lt ? score : s1_1;

            if ((i & 3) == 0) {               // static under unroll 4
                const int irow = g * 16 + (i >> 2);   // row 0..63
                const int kk = __builtin_amdgcn_readlane(k1_0, irow);
                vf4 v;
                v.x = (kk == e0    ) ? 1.f : 0.f;
                v.y = (kk == e0 + 1) ? 1.f : 0.f;
                v.z = (kk == e0 + 2) ? 1.f : 0.f;
                v.w = (kk == e0 + 3) ? 1.f : 0.f;
                const size_t row = (size_t)(bw0 + irow) * C_ + c;
                ((vf4*)(out_onehot + row * K_))[lane] = v;
            }
        }
    }

    // ---- repair j1 + its writes (as R8) ----
    repair_amb(xf1, k1_1, s1_1, s2_1, s_cbf, lane);
    {
        const size_t pair = (size_t)(bbase + TPB + tid) * C_ + c;
        float4* dst = (float4*)(out_embed + pair * D_);
        dst[0] = ((const float4*)s_cbf)[k1_1 * 2];
        dst[1] = ((const float4*)s_cbf)[k1_1 * 2 + 1];
    }
    {
        const int bw1 = bbase + TPB + wave * 64;
        #pragma unroll 8
        for (int i = 0; i < 64; ++i) {
            const int kk = __builtin_amdgcn_readlane(k1_1, i);
            vf4 v;
            v.x = (kk == e0    ) ? 1.f : 0.f;
            v.y = (kk == e0 + 1) ? 1.f : 0.f;
            v.z = (kk == e0 + 2) ? 1.f : 0.f;
            v.w = (kk == e0 + 3) ? 1.f : 0.f;
            const size_t row = (size_t)(bw1 + i) * C_ + c;
            ((vf4*)(out_onehot + row * K_))[lane] = v;
        }
    }
}

extern "C" void kernel_launch(void* const* d_in, const int* in_sizes, int n_in,
                              void* d_out, int out_size, void* d_ws, size_t ws_size,
                              hipStream_t stream) {
    const float* x  = (const float*)d_in[0];
    const float* cb = (const float*)d_in[1];
    float* out        = (float*)d_out;
    float* out_embed  = out;                          // 4096*1024
    float* out_onehot = out + (size_t)B_ * C_ * D_;   // 4096*128*256

    dim3 grid(C_, B_ / BTILE);  // (128, 8) = 1024 blocks, 4 per CU
    vq_fused<<<grid, TPB, 0, stream>>>(x, cb, out_embed, out_onehot);
}

// Round 3
// 593.744 us; speedup vs baseline: 1.0510x; 1.0226x over previous
//
#include <hip/hip_runtime.h>

// VQ-VAE codebook quantization — R15: BPT=4 (halve the LDS broadcast cost).
// x: (4096, 1024) f32; codebook: (128, 256, 8) f32.
// out = [cw_embed (4096*1024 f32) | one_hot (4096*128*256 f32)].
//
// Post-mortems: R13 (SMEM screen, 624us): s_load+ds_read share lgkmcnt,
// out-of-order SMEM forces lgkmcnt(0)/iter. R14 (readlane screen, 607us):
// launch_bounds(,4) VGPR cap + cwreg[36] + fp64 repair doubles -> spills;
// readlane->SGPR->VALU hazards. Both confirm: keep the LDS fused screen.
//
// R15 theory: screen is LDS-return-pipe bound and the pipe is CU-wide.
// Per k per wave: 2x ds_read_b128 + 1x ds_read_b32 ~= 30 cyc of LDS pipe;
// x16 waves x256 k ~= 51us per CU (VALU only ~26us) = exactly the R8 gap
// (142 kernel - 91 write floor). Cost scales 1/BPT (read shared across a
// thread's pairs). BPT 2->4 halves it: LDS ~26us, VALU ~26us (balanced;
// BPT=8 would gain nothing and blow registers). Grid (128,4)=512 blocks,
// 2/CU, 8 waves/CU — still saturates the store drain.
//
// Unchanged from R8 (proven exact, absmax 0.0 across R2-R14): fp32 top-2
// fmaf chain order, LDS s_cbf/s_c2f staging, wave-cooperative fp64 repair
// of gap<=TAU2 pairs, cached full-line one-hot bursts, 32B embed stores.
// NO launch_bounds min-waves (R14's spill trap).

constexpr int B_  = 4096;
constexpr int C_  = 128;
constexpr int K_  = 256;
constexpr int D_  = 8;
constexpr int TPB = 256;

constexpr int   BPT   = 4;           // pairs per thread (R8: 2)
constexpr int   BTILE = TPB * BPT;   // 1024 b per block
constexpr float TAU2  = 1.0e-3f;     // ambiguity gap threshold

typedef float vf4 __attribute__((ext_vector_type(4)));

// Wave-cooperative exact fp64 re-argmin of ambiguous rows (identical to R8).
__device__ __forceinline__ void repair_amb(
    const float xfj[D_], int& k1j, const float s1j, const float s2j,
    const float* s_cbf, const int lane)
{
    const bool amb = (s2j - s1j) <= TAU2;
    unsigned long long mask = __ballot(amb);
    while (mask) {
        const int src = (int)__ffsll((long long)mask) - 1;
        mask &= mask - 1;
        double xd[D_];
        #pragma unroll
        for (int d = 0; d < D_; ++d) xd[d] = (double)__shfl(xfj[d], src);
        double best = 1.0e300;
        int    bk   = 0;
        #pragma unroll
        for (int t = 0; t < 4; ++t) {
            const int k = lane * 4 + t;      // ascending k within lane
            const float* cv = s_cbf + k * D_;
            double cd[D_];
            #pragma unroll
            for (int d = 0; d < D_; ++d) cd[d] = (double)cv[d];
            double c2k = 0.0;
            #pragma unroll
            for (int d = 0; d < D_; ++d) c2k = fma(cd[d], cd[d], c2k);
            double dot = xd[0] * cd[0];
            #pragma unroll
            for (int d = 1; d < D_; ++d) dot = fma(xd[d], cd[d], dot);
            const double score = fma(-2.0, dot, c2k);
            if (score < best) { best = score; bk = k; }  // first-min
        }
        #pragma unroll
        for (int off = 32; off >= 1; off >>= 1) {
            const double ob  = __shfl_down(best, off);
            const int    obk = __shfl_down(bk,   off);
            if (ob < best) { best = ob; bk = obk; }  // tie -> lower k
        }
        const int win = __shfl(bk, 0);
        if (lane == src) k1j = win;
    }
}

__global__ __launch_bounds__(TPB) void vq_fused(
    const float* __restrict__ x,
    const float* __restrict__ cb,
    float* __restrict__ out_embed,
    float* __restrict__ out_onehot)
{
    __shared__ float s_cbf[K_ * D_];  // 8 KB fp32 codebook slice
    __shared__ float s_c2f[K_];       // 1 KB fp32 ||c_k||^2

    const int c    = blockIdx.x;   // 0..127
    const int bt   = blockIdx.y;   // 0..3
    const int tid  = threadIdx.x;
    const int lane = tid & 63;
    const int wave = tid >> 6;

    // ---- stage codebook slice + c2 ----
    {
        const float4* gcb = (const float4*)(cb + (size_t)c * (K_ * D_));
        ((float4*)s_cbf)[tid]       = gcb[tid];
        ((float4*)s_cbf)[tid + TPB] = gcb[tid + TPB];
    }
    __syncthreads();
    {
        const float* v = s_cbf + tid * D_;
        float s = 0.f;
        #pragma unroll
        for (int d = 0; d < D_; ++d) s = fmaf(v[d], v[d], s);
        s_c2f[tid] = s;
    }
    __syncthreads();
    // LDS read-only below; k1 lives in registers — no more barriers.

    const float4* scb4 = (const float4*)s_cbf;
    const int bbase = bt * BTILE;

    // ---- x fragments (4 pairs) ----
    float xf[BPT][D_];
    #pragma unroll
    for (int j = 0; j < BPT; ++j) {
        const int b = bbase + j * TPB + tid;
        const float4* xp = (const float4*)(x + (size_t)b * (C_ * D_) + c * D_);
        const float4 a = xp[0];
        const float4 h = xp[1];
        xf[j][0] = a.x; xf[j][1] = a.y; xf[j][2] = a.z; xf[j][3] = a.w;
        xf[j][4] = h.x; xf[j][5] = h.y; xf[j][6] = h.z; xf[j][7] = h.w;
    }

    // ---- fp32 top-2 screen: one LDS broadcast read shared by 4 pairs ----
    float s1[BPT], s2[BPT];
    int   k1[BPT];
    #pragma unroll
    for (int j = 0; j < BPT; ++j) { s1[j] = 3.4e38f; s2[j] = 3.4e38f; k1[j] = 0; }

    #pragma unroll 2
    for (int k = 0; k < K_; ++k) {
        const float4 clo = scb4[k * 2];
        const float4 chi = scb4[k * 2 + 1];
        const float  c2k = s_c2f[k];
        #pragma unroll
        for (int j = 0; j < BPT; ++j) {
            float dot = xf[j][0] * clo.x;
            dot = fmaf(xf[j][1], clo.y, dot);
            dot = fmaf(xf[j][2], clo.z, dot);
            dot = fmaf(xf[j][3], clo.w, dot);
            dot = fmaf(xf[j][4], chi.x, dot);
            dot = fmaf(xf[j][5], chi.y, dot);
            dot = fmaf(xf[j][6], chi.z, dot);
            dot = fmaf(xf[j][7], chi.w, dot);
            const float score = fmaf(-2.f, dot, c2k);
            // top-2 (s2 uses OLD s1; strict < keeps first-index winner)
            s2[j] = fminf(s2[j], fmaxf(score, s1[j]));
            const bool lt = score < s1[j];
            k1[j] = lt ? k : k1[j];
            s1[j] = lt ? score : s1[j];
        }
    }

    // ---- inline fp64 repair of ambiguous pairs (wave-cooperative) ----
    #pragma unroll
    for (int j = 0; j < BPT; ++j) {
        repair_amb(xf[j], k1[j], s1[j], s2[j], s_cbf, lane);
    }

    // ---- writes (cached; full lines per 8 lanes, no RMW on one-hot) ----
    #pragma unroll
    for (int j = 0; j < BPT; ++j) {
        // embed: own pair, 32B from LDS slice; L2 merges half-lines across
        // adjacent-c blocks (cached stores).
        const int    b    = bbase + j * TPB + tid;
        const size_t pair = (size_t)b * C_ + c;
        float4* dst = (float4*)(out_embed + pair * D_);
        dst[0] = ((const float4*)s_cbf)[k1[j] * 2];
        dst[1] = ((const float4*)s_cbf)[k1[j] * 2 + 1];

        // one-hot: wave writes its 64 lanes' rows; each store instruction is
        // one contiguous 1KB burst (16 full lines).
        const int bw = bbase + j * TPB + wave * 64;
        const int e0 = lane * 4;
        #pragma unroll 8
        for (int i = 0; i < 64; ++i) {
            const int k = __builtin_amdgcn_readlane(k1[j], i);
            vf4 v;
            v.x = (k == e0    ) ? 1.f : 0.f;
            v.y = (k == e0 + 1) ? 1.f : 0.f;
            v.z = (k == e0 + 2) ? 1.f : 0.f;
            v.w = (k == e0 + 3) ? 1.f : 0.f;
            const size_t row = (size_t)(bw + i) * C_ + c;
            ((vf4*)(out_onehot + row * K_))[lane] = v;
        }
    }
}

extern "C" void kernel_launch(void* const* d_in, const int* in_sizes, int n_in,
                              void* d_out, int out_size, void* d_ws, size_t ws_size,
                              hipStream_t stream) {
    const float* x  = (const float*)d_in[0];
    const float* cb = (const float*)d_in[1];
    float* out        = (float*)d_out;
    float* out_embed  = out;                          // 4096*1024
    float* out_onehot = out + (size_t)B_ * C_ * D_;   // 4096*128*256

    dim3 grid(C_, B_ / BTILE);  // (128, 4) = 512 blocks, 2 per CU
    vq_fused<<<grid, TPB, 0, stream>>>(x, cb, out_embed, out_onehot);
}